// Round 4
// baseline (709.376 us; speedup 1.0000x reference)
//
#include <hip/hip_runtime.h>
#include <hip/hip_bf16.h>

#define EMB 1024
#define HEADS 16
#define HDIM 64
#define FFDIM 4096
#define BSZ 4
#define SEQ 2048
#define MROWS (BSZ * SEQ)
#define QBLK 64
#define KVB 64

typedef __attribute__((ext_vector_type(8))) short bf16x8;
typedef __attribute__((ext_vector_type(4))) float f32x4;
typedef __attribute__((ext_vector_type(4))) unsigned short u16x4;
typedef unsigned short u16;

__device__ __forceinline__ float bf2f(u16 u) {
  union { unsigned int i; float f; } c; c.i = ((unsigned int)u) << 16; return c.f;
}
__device__ __forceinline__ u16 f2bf(float f) {
  union { float f; unsigned int i; } c; c.f = f;
  unsigned int i = c.i + 0x7fff + ((c.i >> 16) & 1);
  return (u16)(i >> 16);
}
__device__ __forceinline__ void gload16(const u16* g, void* lds) {
  __builtin_amdgcn_global_load_lds(
      (const __attribute__((address_space(1))) void*)g,
      (__attribute__((address_space(3))) void*)lds, 16, 0, 0);
}

// ---- LayerNorm: f32 in -> bf16 out, one wave per row (4 rows/block) ------
__global__ __launch_bounds__(256) void ln_kernel(
    const float* __restrict__ x, const float* __restrict__ g,
    const float* __restrict__ be, u16* __restrict__ out) {
  int w = threadIdx.x >> 6, l = threadIdx.x & 63;
  size_t row = (size_t)blockIdx.x * 4 + w;
  const float* xr = x + row * EMB;
  float f[4][4];
  float s = 0.f, s2 = 0.f;
#pragma unroll
  for (int c = 0; c < 4; ++c) {
    f32x4 v = *(const f32x4*)(xr + c * 256 + l * 4);
#pragma unroll
    for (int j = 0; j < 4; ++j) {
      f[c][j] = v[j];
      s += v[j];
      s2 += v[j] * v[j];
    }
  }
#pragma unroll
  for (int m = 1; m < 64; m <<= 1) {
    s  += __shfl_xor(s, m);
    s2 += __shfl_xor(s2, m);
  }
  float mu = s * (1.f / EMB);
  float var = s2 * (1.f / EMB) - mu * mu;
  float rs = rsqrtf(var + 1e-5f);
#pragma unroll
  for (int c = 0; c < 4; ++c) {
    u16x4 o;
#pragma unroll
    for (int j = 0; j < 4; ++j) {
      int col = c * 256 + l * 4 + j;
      o[j] = f2bf((f[c][j] - mu) * rs * g[col] + be[col]);
    }
    *(u16x4*)(out + row * EMB + c * 256 + l * 4) = o;
  }
}

// ---- convert+transpose: f32 [R][C] -> bf16 [C][R] ------------------------
__global__ __launch_bounds__(256) void transpose_cvt(
    const float* __restrict__ in, u16* __restrict__ out, int R, int C) {
  __shared__ u16 tile[32][33];
  int c0 = blockIdx.x * 32, r0 = blockIdx.y * 32;
  int tx = threadIdx.x, ty = threadIdx.y;
#pragma unroll
  for (int i = ty; i < 32; i += 8)
    tile[i][tx] = f2bf(in[(size_t)(r0 + i) * C + c0 + tx]);
  __syncthreads();
#pragma unroll
  for (int i = ty; i < 32; i += 8)
    out[(size_t)(c0 + i) * R + r0 + tx] = tile[tx][i];
}

// ---- GEMM: A[M,K]bf16 x Bt[N,K]bf16 + bias(f32) (+gelu / +res f32) -------
__device__ __forceinline__ float gelu_f(float v) {
  float inner = 0.7978845608028654f * (v + 0.044715f * v * v * v);
  return 0.5f * v * (1.f + tanhf(inner));
}

template <int EPI, typename OT>  // bit0: +res, bit1: gelu
__global__ __launch_bounds__(256) void gemm_bt(
    const u16* __restrict__ A, const u16* __restrict__ Bt,
    const float* __restrict__ bias, const float* __restrict__ res,
    OT* __restrict__ C, int N, int K) {
  __shared__ u16 As[128 * 32];
  __shared__ u16 Bs[128 * 32];
  int nb = N >> 7;
  int mb = blockIdx.x / nb, nbi = blockIdx.x % nb;
  int m0 = mb << 7, n0 = nbi << 7;
  int t = threadIdx.x, l = t & 63, lg = l >> 4, lc = l & 15;
  int w = t >> 6;
  int wr = w >> 1, wc = w & 1;
  f32x4 acc[4][4] = {};
  int sr = t >> 2, sc = (t & 3) * 8;
  const u16* Ag = A + (size_t)(m0 + sr) * K + sc;
  const u16* Bg = Bt + (size_t)(n0 + sr) * K + sc;
  char* AsB = (char*)As + w * 1024;
  char* BsB = (char*)Bs + w * 1024;
  for (int k0 = 0; k0 < K; k0 += 32) {
    __syncthreads();  // previous iteration's LDS reads complete
    gload16(Ag + k0, AsB);
    gload16(Ag + k0 + (size_t)64 * K, AsB + 4096);
    gload16(Bg + k0, BsB);
    gload16(Bg + k0 + (size_t)64 * K, BsB + 4096);
    __syncthreads();  // staging complete (barrier drains vmcnt)
    bf16x8 af[4], bfv[4];
#pragma unroll
    for (int i = 0; i < 4; ++i)
      af[i] = *(const bf16x8*)(As + (wr * 64 + i * 16 + lc) * 32 + lg * 8);
#pragma unroll
    for (int j = 0; j < 4; ++j)
      bfv[j] = *(const bf16x8*)(Bs + (wc * 64 + j * 16 + lc) * 32 + lg * 8);
#pragma unroll
    for (int i = 0; i < 4; ++i)
#pragma unroll
      for (int j = 0; j < 4; ++j)
        acc[i][j] = __builtin_amdgcn_mfma_f32_16x16x32_bf16(af[i], bfv[j], acc[i][j], 0, 0, 0);
  }
#pragma unroll
  for (int i = 0; i < 4; ++i)
#pragma unroll
    for (int j = 0; j < 4; ++j) {
      int col = n0 + wc * 64 + j * 16 + lc;
      float bcol = bias[col];
#pragma unroll
      for (int r = 0; r < 4; ++r) {
        int row = m0 + wr * 64 + i * 16 + lg * 4 + r;
        float v = acc[i][j][r] + bcol;
        if (EPI & 2) v = gelu_f(v);
        if (EPI & 1) v += res[(size_t)row * N + col];
        if (sizeof(OT) == 2)
          C[(size_t)row * N + col] = (OT)f2bf(v);
        else
          C[(size_t)row * N + col] = (OT)v;
      }
    }
}

// ---- causal flash attention: 4 waves/block, QBLK=64, KV staged in LDS ----
__global__ __launch_bounds__(256) void attn_kernel(
    const u16* __restrict__ Q, const u16* __restrict__ Kin,
    const u16* __restrict__ V, u16* __restrict__ O) {
  __shared__ u16 Ks[KVB * 64];   // row-major [kv][64], 128B rows, XOR-swizzled
  __shared__ u16 Vt[64 * KVB];   // transposed [d][kv], 128B rows, XOR-swizzled
  __shared__ u16 Ps[4][16 * 64]; // per-wave P [qrow][kv], 128B rows, swizzled
  int t = threadIdx.x, w = t >> 6, l = t & 63, lg = l >> 4, lc = l & 15;
  int nq = SEQ / QBLK;
  int qb = blockIdx.x % nq, bh = blockIdx.x / nq;
  int h = bh % HEADS, b = bh / HEADS;
  int q0 = qb * QBLK;
  int wq0 = q0 + w * 16;
  const u16* Qp = Q + (size_t)b * SEQ * EMB + h * HDIM;
  const u16* Kp = Kin + (size_t)b * SEQ * EMB + h * HDIM;
  const u16* Vp = V + (size_t)b * SEQ * EMB + h * HDIM;
  u16* Op = O + (size_t)b * SEQ * EMB + h * HDIM;
  char* KsB = (char*)Ks;
  char* VtB = (char*)Vt;
  char* PsB = (char*)&Ps[w][0];

  bf16x8 aq0 = *(const bf16x8*)(Qp + (size_t)(wq0 + lc) * EMB + lg * 8);
  bf16x8 aq1 = *(const bf16x8*)(Qp + (size_t)(wq0 + lc) * EMB + 32 + lg * 8);

  f32x4 acc[4] = {};
  float mrow[4], lrow[4];
#pragma unroll
  for (int r = 0; r < 4; ++r) { mrow[r] = -1e30f; lrow[r] = 0.f; }

  int sr_ = t >> 3, sc_ = (t & 7) * 8;  // staging: row 0..31, col group

  for (int kv0 = 0; kv0 < q0 + QBLK; kv0 += KVB) {
    // -------- cooperative staging of K and V^T tiles --------
    bf16x8 k0v = *(const bf16x8*)(Kp + (size_t)(kv0 + sr_) * EMB + sc_);
    bf16x8 k1v = *(const bf16x8*)(Kp + (size_t)(kv0 + sr_ + 32) * EMB + sc_);
    bf16x8 v0v = *(const bf16x8*)(Vp + (size_t)(kv0 + sr_) * EMB + sc_);
    bf16x8 v1v = *(const bf16x8*)(Vp + (size_t)(kv0 + sr_ + 32) * EMB + sc_);
    __syncthreads();  // all waves done reading previous tile
    *(bf16x8*)(KsB + ((sr_ * 128 + sc_ * 2) ^ ((sr_ & 7) << 4))) = k0v;
    *(bf16x8*)(KsB + (((sr_ + 32) * 128 + sc_ * 2) ^ ((sr_ & 7) << 4))) = k1v;
#pragma unroll
    for (int i = 0; i < 8; ++i) {
      int d = sc_ + i;
      *(u16*)(VtB + ((d * 128 + sr_ * 2) ^ ((d & 7) << 4))) = (u16)v0v[i];
      *(u16*)(VtB + ((d * 128 + (sr_ + 32) * 2) ^ ((d & 7) << 4))) = (u16)v1v[i];
    }
    __syncthreads();  // staging complete
    if (kv0 <= wq0 + 15) {
      // -------- QK^T: 4 column groups of 16 --------
      f32x4 sg[4];
#pragma unroll
      for (int g = 0; g < 4; ++g) {
        int row = g * 16 + lc;
        int o0 = (row * 128 + lg * 16) ^ ((row & 7) << 4);
        int o1 = (row * 128 + 64 + lg * 16) ^ ((row & 7) << 4);
        bf16x8 bk0 = *(const bf16x8*)(KsB + o0);
        bf16x8 bk1 = *(const bf16x8*)(KsB + o1);
        f32x4 z = {0.f, 0.f, 0.f, 0.f};
        z = __builtin_amdgcn_mfma_f32_16x16x32_bf16(aq0, bk0, z, 0, 0, 0);
        sg[g] = __builtin_amdgcn_mfma_f32_16x16x32_bf16(aq1, bk1, z, 0, 0, 0);
      }
      // -------- online softmax over the 64 columns --------
#pragma unroll
      for (int r = 0; r < 4; ++r) {
        int prow = lg * 4 + r;
        int arow = wq0 + prow;
        float v[4];
#pragma unroll
        for (int g = 0; g < 4; ++g) {
          v[g] = sg[g][r] * 0.125f;
          if (kv0 + g * 16 + lc > arow) v[g] = -1e30f;
        }
        float tm = fmaxf(fmaxf(v[0], v[1]), fmaxf(v[2], v[3]));
#pragma unroll
        for (int mm = 1; mm < 16; mm <<= 1) tm = fmaxf(tm, __shfl_xor(tm, mm));
        float nm = fmaxf(mrow[r], tm);
        float e[4], ts = 0.f;
#pragma unroll
        for (int g = 0; g < 4; ++g) { e[g] = __expf(v[g] - nm); ts += e[g]; }
#pragma unroll
        for (int mm = 1; mm < 16; mm <<= 1) ts += __shfl_xor(ts, mm);
        float scl = __expf(mrow[r] - nm);
        lrow[r] = lrow[r] * scl + ts;
        mrow[r] = nm;
#pragma unroll
        for (int dc = 0; dc < 4; ++dc) acc[dc][r] *= scl;
#pragma unroll
        for (int g = 0; g < 4; ++g)
          *(u16*)(PsB + ((prow * 128 + (g * 16 + lc) * 2) ^ ((prow & 7) << 4))) = f2bf(e[g]);
      }
      // -------- PV: P[16x64] x V[64x64] --------
#pragma unroll
      for (int s = 0; s < 2; ++s) {
        int po = (lc * 128 + s * 64 + lg * 16) ^ ((lc & 7) << 4);
        bf16x8 ap = *(const bf16x8*)(PsB + po);
#pragma unroll
        for (int dc = 0; dc < 4; ++dc) {
          int vrow = dc * 16 + lc;
          int vo = (vrow * 128 + s * 64 + lg * 16) ^ ((vrow & 7) << 4);
          bf16x8 bv = *(const bf16x8*)(VtB + vo);
          acc[dc] = __builtin_amdgcn_mfma_f32_16x16x32_bf16(ap, bv, acc[dc], 0, 0, 0);
        }
      }
    }
  }
#pragma unroll
  for (int dc = 0; dc < 4; ++dc)
#pragma unroll
    for (int r = 0; r < 4; ++r) {
      int row = wq0 + lg * 4 + r;
      Op[(size_t)row * EMB + dc * 16 + lc] = f2bf(acc[dc][r] / lrow[r]);
    }
}

// ---- driver ---------------------------------------------------------------
extern "C" void kernel_launch(void* const* d_in, const int* in_sizes, int n_in,
                              void* d_out, int out_size, void* d_ws, size_t ws_size,
                              hipStream_t stream) {
  (void)in_sizes; (void)n_in; (void)out_size; (void)ws_size;
  const float* x   = (const float*)d_in[0];
  const float* Wq  = (const float*)d_in[1];
  const float* bq  = (const float*)d_in[2];
  const float* Wk  = (const float*)d_in[3];
  const float* bk  = (const float*)d_in[4];
  const float* Wv  = (const float*)d_in[5];
  const float* bv  = (const float*)d_in[6];
  const float* Wo  = (const float*)d_in[7];
  const float* bo  = (const float*)d_in[8];
  const float* W1  = (const float*)d_in[9];
  const float* b1  = (const float*)d_in[10];
  const float* W2  = (const float*)d_in[11];
  const float* b2  = (const float*)d_in[12];
  const float* g1  = (const float*)d_in[13];
  const float* be1 = (const float*)d_in[14];
  const float* g2  = (const float*)d_in[15];
  const float* be2 = (const float*)d_in[16];

  char* ws = (char*)d_ws;
  const size_t MB = 1ull << 20;
  u16*   WqT  = (u16*)(ws + 0 * MB);     // 2 MB
  u16*   WkT  = (u16*)(ws + 2 * MB);     // 2 MB
  u16*   WvT  = (u16*)(ws + 4 * MB);     // 2 MB
  u16*   WoT  = (u16*)(ws + 6 * MB);     // 2 MB
  u16*   W1T  = (u16*)(ws + 8 * MB);     // 8 MB
  u16*   W2T  = (u16*)(ws + 16 * MB);    // 8 MB
  u16*   hbuf = (u16*)(ws + 24 * MB);    // 16 MB: LN1 out, later ctx
  u16*   Kbuf = (u16*)(ws + 40 * MB);    // 16 MB: K, later h2
  float* x1f  = (float*)(ws + 56 * MB);  // 32 MB: attn residual out (f32)
  u16*   Qbuf = (u16*)(ws + 88 * MB);    // 16 MB: Q (dead after attn)
  u16*   Vbuf = (u16*)(ws + 104 * MB);   // 16 MB: V (dead after attn)
  u16*   gbuf = (u16*)(ws + 88 * MB);    // 64 MB: FF1 out (overlaps dead Q,V)

  dim3 tb(32, 8);
  transpose_cvt<<<dim3(EMB / 32, EMB / 32), tb, 0, stream>>>(Wq, WqT, EMB, EMB);
  transpose_cvt<<<dim3(EMB / 32, EMB / 32), tb, 0, stream>>>(Wk, WkT, EMB, EMB);
  transpose_cvt<<<dim3(EMB / 32, EMB / 32), tb, 0, stream>>>(Wv, WvT, EMB, EMB);
  transpose_cvt<<<dim3(EMB / 32, EMB / 32), tb, 0, stream>>>(Wo, WoT, EMB, EMB);
  transpose_cvt<<<dim3(FFDIM / 32, EMB / 32), tb, 0, stream>>>(W1, W1T, EMB, FFDIM);
  transpose_cvt<<<dim3(EMB / 32, FFDIM / 32), tb, 0, stream>>>(W2, W2T, FFDIM, EMB);

  ln_kernel<<<MROWS / 4, 256, 0, stream>>>(x, g1, be1, hbuf);

  const int GQKV = (MROWS / 128) * (EMB / 128);    // 512
  const int GFF1 = (MROWS / 128) * (FFDIM / 128);  // 2048
  gemm_bt<0, u16><<<GQKV, 256, 0, stream>>>(hbuf, WqT, bq, nullptr, Qbuf, EMB, EMB);
  gemm_bt<0, u16><<<GQKV, 256, 0, stream>>>(hbuf, WkT, bk, nullptr, Kbuf, EMB, EMB);
  gemm_bt<0, u16><<<GQKV, 256, 0, stream>>>(hbuf, WvT, bv, nullptr, Vbuf, EMB, EMB);

  attn_kernel<<<BSZ * HEADS * (SEQ / QBLK), 256, 0, stream>>>(Qbuf, Kbuf, Vbuf, hbuf);

  gemm_bt<1, float><<<GQKV, 256, 0, stream>>>(hbuf, WoT, bo, x, x1f, EMB, EMB);

  ln_kernel<<<MROWS / 4, 256, 0, stream>>>(x1f, g2, be2, Kbuf);

  gemm_bt<2, u16><<<GFF1, 256, 0, stream>>>(Kbuf, W1T, b1, nullptr, gbuf, FFDIM, EMB);
  gemm_bt<1, float><<<GQKV, 256, 0, stream>>>(gbuf, W2T, b2, x1f, (float*)d_out, EMB, FFDIM);
}